// Round 10
// baseline (40.098 us; speedup 1.0000x reference)
//
#include <hip/hip_runtime.h>
#include <math.h>

typedef float    f32x2 __attribute__((ext_vector_type(2)));
typedef float    f32x4 __attribute__((ext_vector_type(4)));
typedef _Float16 f16x2 __attribute__((ext_vector_type(2)));

static constexpr int B_ = 4;
static constexpr int L_ = 256;
static constexpr int K_ = 256;
static constexpr int H_ = 768;
static constexpr int H2_ = H_ / 2;       // 384 f16-pairs per row
static constexpr int VAL_SIZE_ = 10000;
static constexpr float INV_TEMPER = 0.03608439182435161f; // 1/sqrt(768)

// ---------------- f16 pair helpers ----------------
__device__ __forceinline__ unsigned pack_f16x2(float a, float b) {
  f16x2 p = {(_Float16)a, (_Float16)b};   // RNE converts
  return __builtin_bit_cast(unsigned, p);
}
__device__ __forceinline__ float fdot2u(unsigned a, unsigned b, float c) {
#if __has_builtin(__builtin_amdgcn_fdot2)
  return __builtin_amdgcn_fdot2(__builtin_bit_cast(f16x2, a),
                                __builtin_bit_cast(f16x2, b), c, false);
#else
  f16x2 va = __builtin_bit_cast(f16x2, a);
  f16x2 vb = __builtin_bit_cast(f16x2, b);
  return c + (float)va.x * (float)vb.x + (float)va.y * (float)vb.y;
#endif
}

// ---------------- non-temporal load (native vec type) ----------------
__device__ __forceinline__ float4 nt_load4(const float* p) {
  f32x4 v = __builtin_nontemporal_load(reinterpret_cast<const f32x4*>(p));
  return make_float4(v.x, v.y, v.z, v.w);
}

// ---------------- fp8 e4m3fn (OCP) helpers ----------------
#if __has_builtin(__builtin_amdgcn_cvt_pk_fp8_f32)
#define HW_FP8_ENC 1
#endif
#if __has_builtin(__builtin_amdgcn_cvt_pk_f32_fp8)
#define HW_FP8_DEC 1
#endif

__device__ __forceinline__ unsigned fp8_enc1(float f) {
  unsigned s = (__float_as_uint(f) >> 31) << 7;
  float af = fminf(fabsf(f), 448.0f);
  unsigned em;
  if (af < 0.015625f) {
    em = (unsigned)rintf(af * 512.0f);
  } else {
    unsigned m = __float_as_uint(af);
    m += 0x7ffffu + ((m >> 20) & 1u);
    em = (m >> 20) - (120u << 3);
  }
  return s | em;
}
__device__ __forceinline__ float fp8_dec1(unsigned b) {
  unsigned em = b & 0x7fu;
  unsigned sbit = (b & 0x80u) << 24;
  float n = __uint_as_float(sbit | ((em + 960u) << 20));
  float sub = __uint_as_float(sbit | 0x3F800000u) * (float)em * 0.001953125f;
  return em >= 8u ? n : sub;
}
__device__ __forceinline__ unsigned fp8_enc4(float a, float b, float c, float d) {
#ifdef HW_FP8_ENC
  int w = 0;
  w = __builtin_amdgcn_cvt_pk_fp8_f32(a, b, w, false);
  w = __builtin_amdgcn_cvt_pk_fp8_f32(c, d, w, true);
  return (unsigned)w;
#else
  return fp8_enc1(a) | (fp8_enc1(b) << 8) | (fp8_enc1(c) << 16) | (fp8_enc1(d) << 24);
#endif
}
__device__ __forceinline__ void fp8_dec4(unsigned w, float* o) {
#ifdef HW_FP8_DEC
  f32x2 lo = __builtin_amdgcn_cvt_pk_f32_fp8((int)w, false);
  f32x2 hi = __builtin_amdgcn_cvt_pk_f32_fp8((int)w, true);
  o[0] = lo.x; o[1] = lo.y; o[2] = hi.x; o[3] = hi.y;
#else
  o[0] = fp8_dec1(w & 0xffu);
  o[1] = fp8_dec1((w >> 8) & 0xffu);
  o[2] = fp8_dec1((w >> 16) & 0xffu);
  o[3] = fp8_dec1(w >> 24);
#endif
}

static constexpr int TBLK = (K_ / 64) * (H_ / 64) * B_;    // 192 transpose blocks
static constexpr int CBLK = (VAL_SIZE_ * H_) / 4096;       // 1875 convert shares
static constexpr int FBLK = (L_ / 2) * B_;                 // 512 fused blocks
static constexpr int NCONV_SIG = 2 * FBLK;                 // 2 producer waves/block
static constexpr size_t VT8_BYTES = (size_t)VAL_SIZE_ * H_;     // 7,680,000
static constexpr size_t ET2_BYTES = (size_t)B_ * H2_ * K_ * 4;  // 1,572,864
static constexpr size_t CTR_OFF   = VT8_BYTES + ET2_BYTES;      // 64-aligned

// ---------------------------------------------------------------------------
// Prep kernel: blocks [0,TBLK) gather+transpose keys -> f16-pair ET2;
// blocks >= TBLK (fallback path only) convert val table -> fp8 VT8.
// ---------------------------------------------------------------------------
__global__ __launch_bounds__(256)
void k_prep(const int* __restrict__ key_seq,
            const float* __restrict__ key_emb,
            const float* __restrict__ vtab,
            unsigned* __restrict__ ET2,
            unsigned char* __restrict__ VT8) {
  __shared__ float tile[64][65];
  const int t = threadIdx.x;

  if (blockIdx.x >= TBLK) {
    const size_t base = (size_t)(blockIdx.x - TBLK) * 4096;
#pragma unroll
    for (int c = 0; c < 4; ++c) {
      const size_t e0 = base + (size_t)c * 1024 + (size_t)t * 4;
      const float4 a = nt_load4(vtab + e0);
      *reinterpret_cast<unsigned*>(VT8 + e0) = fp8_enc4(a.x, a.y, a.z, a.w);
    }
    return;
  }

  const int blk  = blockIdx.x;
  const int kb   = (blk % (K_ / 64)) * 64;
  const int hb   = ((blk / (K_ / 64)) % (H_ / 64)) * 64;
  const int b    = blk / ((K_ / 64) * (H_ / 64));
  const int sub  = t >> 6;
  const int lane = t & 63;

#pragma unroll
  for (int p = 0; p < 16; ++p) {
    const int kl  = p * 4 + sub;
    const int row = key_seq[b * K_ + kb + kl];              // wave-uniform
    tile[kl][lane] = key_emb[(size_t)row * H_ + hb + lane]; // coalesced
  }
  __syncthreads();
#pragma unroll
  for (int p = 0; p < 8; ++p) {
    const int hl2 = p * 4 + sub;                            // 0..31
    ET2[((size_t)b * H2_ + (hb >> 1) + hl2) * K_ + kb + lane] =
        pack_f16x2(tile[lane][2 * hl2], tile[lane][2 * hl2 + 1]);
  }
}

// ---------------------------------------------------------------------------
// Fused kernel: 512 blocks x 512 threads (2 blocks/CU enforced by
// __launch_bounds__(512,4); host verifies via occupancy query, else gated=0).
// Waves 0-5: scores (6-wave h-split, self-staged hid2 slices).
// Waves 6-7 (gated=1): convert val-table shares -> VT8, fence, ctr++.
// All: sync -> (waves 0,1 softmax+compact) -> acquire-gate on ctr -> sync
//      -> PV gather + tree combine + residual store.
// ---------------------------------------------------------------------------
__global__ __launch_bounds__(512, 4)
void k_fused(const float* __restrict__ hidden,
             const unsigned* __restrict__ ET2,
             const int* __restrict__ mask,
             const int* __restrict__ vmat,
             const float* __restrict__ vtab,
             unsigned char* __restrict__ VT8,
             float* __restrict__ out,
             unsigned* __restrict__ ctr,
             const int gated) {
  __shared__ unsigned hid2[2 * H2_];     // 3 KB
  __shared__ float4   part[2][6][64];    // 12 KB
  __shared__ int      vmat_lds[2][K_];   // 2 KB
  __shared__ float    pw[2][K_];         // 2 KB
  __shared__ int      vidx[2][K_];       // 2 KB
  __shared__ float    osum[2][2][H_];    // 12 KB
  __shared__ int      nrow[2];

  const int t    = threadIdx.x;
  const int wave = t >> 6;
  const int lane = t & 63;
  const int l0   = ((int)blockIdx.x & 127) * 2;
  const int b    = (int)blockIdx.x >> 7;

  if (wave < 6) {
    // ---- stage own hid2 slice (no cross-wave dependency) ----
    const int hq = wave;                 // h2 in [hq*64, hq*64+64)
    const float* hsrc = hidden + ((size_t)b * L_ + l0) * H_;
#pragma unroll
    for (int l = 0; l < 2; ++l) {
      const float2 hv = *reinterpret_cast<const float2*>(
          hsrc + l * H_ + (hq * 64 + lane) * 2);
      hid2[l * H2_ + hq * 64 + lane] = pack_f16x2(hv.x, hv.y);
    }
    if (t < 128) {                       // waves 0,1 stage vmat (own use)
      const int r  = t >> 6;
      const int c4 = lane * 4;
      *reinterpret_cast<int4*>(&vmat_lds[r][c4]) =
          *reinterpret_cast<const int4*>(
              vmat + ((size_t)b * L_ + l0 + r) * K_ + c4);
    }

    // ---- scores: 64 h2 iters, 2 rows, 4 k each ----
    float4 acc[2];
#pragma unroll
    for (int l = 0; l < 2; ++l) acc[l] = make_float4(0.f, 0.f, 0.f, 0.f);
    const unsigned* etp =
        ET2 + (size_t)b * H2_ * K_ + (size_t)(hq * 64) * K_ + lane * 4;
#pragma unroll 4
    for (int hh = 0; hh < 64; ++hh) {
      const uint4 e = *reinterpret_cast<const uint4*>(etp + (size_t)hh * K_);
#pragma unroll
      for (int l = 0; l < 2; ++l) {
        const unsigned hv2 = hid2[l * H2_ + hq * 64 + hh];  // LDS broadcast
        acc[l].x = fdot2u(e.x, hv2, acc[l].x);
        acc[l].y = fdot2u(e.y, hv2, acc[l].y);
        acc[l].z = fdot2u(e.z, hv2, acc[l].z);
        acc[l].w = fdot2u(e.w, hv2, acc[l].w);
      }
    }
#pragma unroll
    for (int l = 0; l < 2; ++l) part[l][hq][lane] = acc[l];
  } else if (gated) {
    // ---- producers: convert val-table shares f32 -> fp8 ----
    const int s0 = (int)blockIdx.x + (wave == 7 ? FBLK : 0);
#pragma unroll
    for (int rep = 0; rep < 2; ++rep) {
      const int s = s0 + rep * 2 * FBLK;       // shares of 4096 floats
      if (s < CBLK) {
        const size_t base4 = (size_t)s * 1024; // float4 units
#pragma unroll
        for (int i = 0; i < 16; ++i) {
          const size_t idx4 = base4 + (size_t)i * 64 + lane;
          const float4 a = nt_load4(vtab + idx4 * 4);
          *reinterpret_cast<unsigned*>(VT8 + idx4 * 4) =
              fp8_enc4(a.x, a.y, a.z, a.w);
        }
      }
    }
    __threadfence();                           // make VT8 visible device-wide
    if (lane == 0)
      __hip_atomic_fetch_add(ctr, 1u, __ATOMIC_RELEASE,
                             __HIP_MEMORY_SCOPE_AGENT);
  }
  __syncthreads();   // #1: part[] complete (producers arrive after convert)

  // ---- softmax + compaction: waves 0,1 (one per row) ----
  if (t < 128) {
    const int kq2 = lane;
    const int l2  = t >> 6;
    float4 a = part[l2][0][kq2];
#pragma unroll
    for (int c = 1; c < 6; ++c) {
      const float4 pc = part[l2][c][kq2];
      a.x += pc.x; a.y += pc.y; a.z += pc.z; a.w += pc.w;
    }

    const int lrow = l0 + l2;
    const int4 m4 = *reinterpret_cast<const int4*>(
        mask + ((size_t)b * L_ + lrow) * K_ + kq2 * 4);
    float ex[4];
    ex[0] = (m4.x > 0) ? expf(a.x * INV_TEMPER) : 0.f;
    ex[1] = (m4.y > 0) ? expf(a.y * INV_TEMPER) : 0.f;
    ex[2] = (m4.z > 0) ? expf(a.z * INV_TEMPER) : 0.f;
    ex[3] = (m4.w > 0) ? expf(a.w * INV_TEMPER) : 0.f;

    float s = ex[0] + ex[1] + ex[2] + ex[3];
#pragma unroll
    for (int off = 32; off > 0; off >>= 1) s += __shfl_down(s, off);
    const float tot = __shfl(s, 0) + 1e-10f;
    const float rtot = 1.0f / tot;

    const unsigned long long lt = (1ull << kq2) - 1ull;
    unsigned long long m[4];
    int run = 0;
    int pos[4];
#pragma unroll
    for (int cc = 0; cc < 4; ++cc) {
      m[cc] = __ballot(ex[cc] != 0.f);
      pos[cc] = run + (int)__popcll(m[cc] & lt);
      run += (int)__popcll(m[cc]);
    }
#pragma unroll
    for (int cc = 0; cc < 4; ++cc) {
      if (ex[cc] != 0.f) {
        pw[l2][pos[cc]]   = ex[cc] * rtot;
        vidx[l2][pos[cc]] = vmat_lds[l2][kq2 * 4 + cc];
      }
    }
    if (kq2 == 0) nrow[l2] = run;
  }

  // ---- gate: VT8 complete (each wave acquires; waves 2-7 spin during
  //      softmax above). Fallback path: VT8 valid from k_prep. ----
  if (gated) {
    while (__hip_atomic_load(ctr, __ATOMIC_ACQUIRE,
                             __HIP_MEMORY_SCOPE_AGENT) < (unsigned)NCONV_SIG)
      __builtin_amdgcn_s_sleep(2);
  }
  __syncthreads();   // #2: pw/vidx/nrow visible to all waves

  // ---- PV: wave -> row r=wave&1, quarter q=wave>>1 ----
  const int r = wave & 1;
  const int q = wave >> 1;       // 0..3
  const int n = nrow[r];

  float acc[12];
#pragma unroll
  for (int i = 0; i < 12; ++i) acc[i] = 0.f;

#pragma unroll 4
  for (int j = q; j < n; j += 4) {
    const float wgt = pw[r][j];                   // LDS broadcast
    const int   idx = vidx[r][j];
    const uint3 v = *reinterpret_cast<const uint3*>(
        VT8 + (size_t)idx * H_ + lane * 12);      // 12B x 64 lanes = 768B row
    float f[12];
    fp8_dec4(v.x, f);
    fp8_dec4(v.y, f + 4);
    fp8_dec4(v.z, f + 8);
#pragma unroll
    for (int i = 0; i < 12; ++i) acc[i] += wgt * f[i];
  }

  if (q < 2) {
#pragma unroll
    for (int c = 0; c < 3; ++c)
      *reinterpret_cast<float4*>(&osum[r][q][lane * 12 + c * 4]) =
          make_float4(acc[c * 4], acc[c * 4 + 1], acc[c * 4 + 2], acc[c * 4 + 3]);
  }
  __syncthreads();
  if (q >= 2) {
#pragma unroll
    for (int i = 0; i < 12; ++i) osum[r][q - 2][lane * 12 + i] += acc[i];
  }
  __syncthreads();

  if (q == 0) {
    const float* hrow = hidden + ((size_t)b * L_ + l0 + r) * H_;
    float*       orow = out    + ((size_t)b * L_ + l0 + r) * H_;
#pragma unroll
    for (int c = 0; c < 3; ++c) {
      const int h0 = c * 256 + lane * 4;
      const float4 o0 = *reinterpret_cast<const float4*>(&osum[r][0][h0]);
      const float4 o1 = *reinterpret_cast<const float4*>(&osum[r][1][h0]);
      const float4 hv = *reinterpret_cast<const float4*>(hrow + h0);
      *reinterpret_cast<float4*>(orow + h0) =
          make_float4(o0.x + o1.x + hv.x, o0.y + o1.y + hv.y,
                      o0.z + o1.z + hv.z, o0.w + o1.w + hv.w);
    }
  }
}

// ---------------------------------------------------------------------------
extern "C" void kernel_launch(void* const* d_in, const int* in_sizes, int n_in,
                              void* d_out, int out_size, void* d_ws, size_t ws_size,
                              hipStream_t stream) {
  (void)in_sizes; (void)n_in; (void)out_size; (void)ws_size;
  const float* hidden  = (const float*)d_in[0];
  const int*   key_seq = (const int*)d_in[1];
  const int*   vmat    = (const int*)d_in[2];
  const int*   mask    = (const int*)d_in[3];
  const float* key_emb = (const float*)d_in[4];
  const float* val_emb = (const float*)d_in[5];
  float* out = (float*)d_out;

  // ws layout: VT8 | ET2 | ctr (64B)
  unsigned char* VT8 = (unsigned char*)d_ws;
  unsigned*      ET2 = (unsigned*)(VT8 + VT8_BYTES);
  unsigned*      ctr = (unsigned*)((char*)d_ws + CTR_OFF);

  // Producer-consumer gating requires all 512 fused blocks co-resident
  // (2 blocks/CU). Verify; otherwise use the safe 2-kernel path.
  int occ = 0;
  hipError_t e = hipOccupancyMaxActiveBlocksPerMultiprocessor(&occ, k_fused, 512, 0);
  const bool gated = (e == hipSuccess && occ >= 2);

  hipMemsetAsync(ctr, 0, 64, stream);
  if (gated) {
    k_prep<<<TBLK, 256, 0, stream>>>(key_seq, key_emb, val_emb, ET2, VT8);
    k_fused<<<FBLK, 512, 0, stream>>>(hidden, ET2, mask, vmat, val_emb, VT8,
                                      out, ctr, 1);
  } else {
    k_prep<<<TBLK + CBLK, 256, 0, stream>>>(key_seq, key_emb, val_emb, ET2, VT8);
    k_fused<<<FBLK, 512, 0, stream>>>(hidden, ET2, mask, vmat, val_emb, VT8,
                                      out, ctr, 0);
  }
}

// Round 11
// 38.386 us; speedup vs baseline: 1.0446x; 1.0446x over previous
//
#include <hip/hip_runtime.h>
#include <math.h>

typedef float    f32x2 __attribute__((ext_vector_type(2)));
typedef float    f32x4 __attribute__((ext_vector_type(4)));
typedef _Float16 f16x2 __attribute__((ext_vector_type(2)));

static constexpr int B_ = 4;
static constexpr int L_ = 256;
static constexpr int K_ = 256;
static constexpr int H_ = 768;
static constexpr int H2_ = H_ / 2;       // 384 f16-pairs per row
static constexpr int VAL_SIZE_ = 10000;
static constexpr float INV_TEMPER = 0.03608439182435161f; // 1/sqrt(768)

// ---------------- f16 pair helpers ----------------
__device__ __forceinline__ unsigned pack_f16x2(float a, float b) {
  f16x2 p = {(_Float16)a, (_Float16)b};   // RNE converts
  return __builtin_bit_cast(unsigned, p);
}
__device__ __forceinline__ float fdot2u(unsigned a, unsigned b, float c) {
#if __has_builtin(__builtin_amdgcn_fdot2)
  return __builtin_amdgcn_fdot2(__builtin_bit_cast(f16x2, a),
                                __builtin_bit_cast(f16x2, b), c, false);
#else
  f16x2 va = __builtin_bit_cast(f16x2, a);
  f16x2 vb = __builtin_bit_cast(f16x2, b);
  return c + (float)va.x * (float)vb.x + (float)va.y * (float)vb.y;
#endif
}

// ---------------- non-temporal load (native vec type) ----------------
__device__ __forceinline__ float4 nt_load4(const float* p) {
  f32x4 v = __builtin_nontemporal_load(reinterpret_cast<const f32x4*>(p));
  return make_float4(v.x, v.y, v.z, v.w);
}

// ---------------- fp8 e4m3fn (OCP) helpers ----------------
#if __has_builtin(__builtin_amdgcn_cvt_pk_fp8_f32)
#define HW_FP8_ENC 1
#endif
#if __has_builtin(__builtin_amdgcn_cvt_pk_f32_fp8)
#define HW_FP8_DEC 1
#endif

__device__ __forceinline__ unsigned fp8_enc1(float f) {
  unsigned s = (__float_as_uint(f) >> 31) << 7;
  float af = fminf(fabsf(f), 448.0f);
  unsigned em;
  if (af < 0.015625f) {
    em = (unsigned)rintf(af * 512.0f);
  } else {
    unsigned m = __float_as_uint(af);
    m += 0x7ffffu + ((m >> 20) & 1u);
    em = (m >> 20) - (120u << 3);
  }
  return s | em;
}
__device__ __forceinline__ float fp8_dec1(unsigned b) {
  unsigned em = b & 0x7fu;
  unsigned sbit = (b & 0x80u) << 24;
  float n = __uint_as_float(sbit | ((em + 960u) << 20));
  float sub = __uint_as_float(sbit | 0x3F800000u) * (float)em * 0.001953125f;
  return em >= 8u ? n : sub;
}
__device__ __forceinline__ unsigned fp8_enc4(float a, float b, float c, float d) {
#ifdef HW_FP8_ENC
  int w = 0;
  w = __builtin_amdgcn_cvt_pk_fp8_f32(a, b, w, false);
  w = __builtin_amdgcn_cvt_pk_fp8_f32(c, d, w, true);
  return (unsigned)w;
#else
  return fp8_enc1(a) | (fp8_enc1(b) << 8) | (fp8_enc1(c) << 16) | (fp8_enc1(d) << 24);
#endif
}
__device__ __forceinline__ void fp8_dec4(unsigned w, float* o) {
#ifdef HW_FP8_DEC
  f32x2 lo = __builtin_amdgcn_cvt_pk_f32_fp8((int)w, false);
  f32x2 hi = __builtin_amdgcn_cvt_pk_f32_fp8((int)w, true);
  o[0] = lo.x; o[1] = lo.y; o[2] = hi.x; o[3] = hi.y;
#else
  o[0] = fp8_dec1(w & 0xffu);
  o[1] = fp8_dec1((w >> 8) & 0xffu);
  o[2] = fp8_dec1((w >> 16) & 0xffu);
  o[3] = fp8_dec1(w >> 24);
#endif
}

static constexpr int TBLK = (K_ / 64) * (H_ / 64) * B_;    // 192 transpose blocks
static constexpr int SBLK = (L_ / 2) * B_;                 // 512 score blocks
static constexpr int CBLK = (VAL_SIZE_ * H_) / 4096;       // 1875 convert blocks
static constexpr size_t VT8_BYTES = (size_t)VAL_SIZE_ * H_;     // 7,680,000
static constexpr size_t ET2_BYTES = (size_t)B_ * H2_ * K_ * 4;  // 1,572,864
static constexpr size_t PW_BYTES  = (size_t)B_ * L_ * K_ * 4;   // 1,048,576
static constexpr size_t VX_BYTES  = PW_BYTES;

// ---------------------------------------------------------------------------
// K1: gather key embedding rows, transpose to f16-pair ET2[b][h2][k].
// grid TBLK, block 256.
// ---------------------------------------------------------------------------
__global__ __launch_bounds__(256)
void k_gather_keys_T(const int* __restrict__ key_seq,
                     const float* __restrict__ key_emb,
                     unsigned* __restrict__ ET2) {
  __shared__ float tile[64][65];
  const int blk  = blockIdx.x;
  const int kb   = (blk % (K_ / 64)) * 64;
  const int hb   = ((blk / (K_ / 64)) % (H_ / 64)) * 64;
  const int b    = blk / ((K_ / 64) * (H_ / 64));
  const int t    = threadIdx.x;
  const int sub  = t >> 6;
  const int lane = t & 63;

#pragma unroll
  for (int p = 0; p < 16; ++p) {
    const int kl  = p * 4 + sub;
    const int row = key_seq[b * K_ + kb + kl];              // wave-uniform
    tile[kl][lane] = key_emb[(size_t)row * H_ + hb + lane]; // coalesced
  }
  __syncthreads();
#pragma unroll
  for (int p = 0; p < 8; ++p) {
    const int hl2 = p * 4 + sub;                            // 0..31
    ET2[((size_t)b * H2_ + (hb >> 1) + hl2) * K_ + kb + lane] =
        pack_f16x2(tile[lane][2 * hl2], tile[lane][2 * hl2 + 1]);
  }
}

// ---------------------------------------------------------------------------
// K2: blocks [0,SBLK): scores + masked softmax + compaction for 2 l-rows,
// writing compacted (pw, vidx, nrow) to global. blocks [SBLK,SBLK+CBLK):
// convert val table f32 -> fp8 (independent; overlaps scores). block 512.
// ---------------------------------------------------------------------------
__global__ __launch_bounds__(512)
void k_scores_conv(const float* __restrict__ hidden,
                   const unsigned* __restrict__ ET2,
                   const int* __restrict__ mask,
                   const int* __restrict__ vmat,
                   const float* __restrict__ vtab,
                   unsigned char* __restrict__ VT8,
                   float* __restrict__ Pw,
                   int* __restrict__ Vx,
                   int* __restrict__ nrowG) {
  __shared__ unsigned hid2[2 * H2_];    // 3 KB
  __shared__ float4   part[2][8][64];   // 16 KB
  __shared__ int      vmat_lds[2][K_];  // 2 KB
  __shared__ float    pw_l[2][K_];      // 2 KB
  __shared__ int      vx_l[2][K_];      // 2 KB
  __shared__ int      nrow_l[2];

  const int t = threadIdx.x;

  if (blockIdx.x >= SBLK) {
    // ---- convert: 4096 contiguous floats per block ----
    const size_t base = (size_t)(blockIdx.x - SBLK) * 4096;
#pragma unroll
    for (int c = 0; c < 2; ++c) {
      const size_t e0 = base + (size_t)c * 2048 + (size_t)t * 4;
      const float4 a = nt_load4(vtab + e0);
      *reinterpret_cast<unsigned*>(VT8 + e0) = fp8_enc4(a.x, a.y, a.z, a.w);
    }
    return;
  }

  const int wave = t >> 6;
  const int lane = t & 63;
  const int l0   = ((int)blockIdx.x & 127) * 2;
  const int b    = (int)blockIdx.x >> 7;

  // ---- stage hidden as f16 pairs + vmat rows ----
  const float* hsrc = hidden + ((size_t)b * L_ + l0) * H_;
  for (int i = t; i < 2 * H2_; i += 512) {
    const float2 hv = *reinterpret_cast<const float2*>(hsrc + 2 * i);
    hid2[i] = pack_f16x2(hv.x, hv.y);
  }
  if (t < 128) {
    const int r  = t >> 6;
    const int c4 = lane * 4;
    *reinterpret_cast<int4*>(&vmat_lds[r][c4]) =
        *reinterpret_cast<const int4*>(vmat + ((size_t)b * L_ + l0 + r) * K_ + c4);
  }
  __syncthreads();

  // ---- scores: 8 waves x 48 h2 (identical numerics to r9) ----
  {
    const int hq = wave;
    float4 acc[2];
#pragma unroll
    for (int l = 0; l < 2; ++l) acc[l] = make_float4(0.f, 0.f, 0.f, 0.f);
    const unsigned* etp =
        ET2 + (size_t)b * H2_ * K_ + (size_t)(hq * 48) * K_ + lane * 4;
#pragma unroll 4
    for (int hh = 0; hh < 48; ++hh) {
      const uint4 e = *reinterpret_cast<const uint4*>(etp + (size_t)hh * K_);
#pragma unroll
      for (int l = 0; l < 2; ++l) {
        const unsigned hv2 = hid2[l * H2_ + hq * 48 + hh];  // LDS broadcast
        acc[l].x = fdot2u(e.x, hv2, acc[l].x);
        acc[l].y = fdot2u(e.y, hv2, acc[l].y);
        acc[l].z = fdot2u(e.z, hv2, acc[l].z);
        acc[l].w = fdot2u(e.w, hv2, acc[l].w);
      }
    }
#pragma unroll
    for (int l = 0; l < 2; ++l) part[l][hq][lane] = acc[l];
  }
  __syncthreads();

  // ---- softmax + compaction: waves 0,1 ----
  if (t < 128) {
    const int kq2 = lane;
    const int l2  = t >> 6;
    float4 a = part[l2][0][kq2];
#pragma unroll
    for (int c = 1; c < 8; ++c) {
      const float4 pc = part[l2][c][kq2];
      a.x += pc.x; a.y += pc.y; a.z += pc.z; a.w += pc.w;
    }

    const int lrow = l0 + l2;
    const int4 m4 = *reinterpret_cast<const int4*>(
        mask + ((size_t)b * L_ + lrow) * K_ + kq2 * 4);
    float ex[4];
    ex[0] = (m4.x > 0) ? expf(a.x * INV_TEMPER) : 0.f;
    ex[1] = (m4.y > 0) ? expf(a.y * INV_TEMPER) : 0.f;
    ex[2] = (m4.z > 0) ? expf(a.z * INV_TEMPER) : 0.f;
    ex[3] = (m4.w > 0) ? expf(a.w * INV_TEMPER) : 0.f;

    float s = ex[0] + ex[1] + ex[2] + ex[3];
#pragma unroll
    for (int off = 32; off > 0; off >>= 1) s += __shfl_down(s, off);
    const float tot = __shfl(s, 0) + 1e-10f;
    const float rtot = 1.0f / tot;

    const unsigned long long lt = (1ull << kq2) - 1ull;
    unsigned long long m[4];
    int run = 0;
    int pos[4];
#pragma unroll
    for (int cc = 0; cc < 4; ++cc) {
      m[cc] = __ballot(ex[cc] != 0.f);
      pos[cc] = run + (int)__popcll(m[cc] & lt);
      run += (int)__popcll(m[cc]);
    }
    // clear tail so copy-out is fully defined
    pw_l[l2][kq2] = 0.f; pw_l[l2][64 + kq2] = 0.f;
    pw_l[l2][128 + kq2] = 0.f; pw_l[l2][192 + kq2] = 0.f;
#pragma unroll
    for (int cc = 0; cc < 4; ++cc) {
      if (ex[cc] != 0.f) {
        pw_l[l2][pos[cc]] = ex[cc] * rtot;
        vx_l[l2][pos[cc]] = vmat_lds[l2][kq2 * 4 + cc];
      }
    }
    if (kq2 == 0) nrow_l[l2] = run;
  }
  __syncthreads();

  // ---- coalesced copy-out ----
  if (t < 128) {
    const int r  = t >> 6;
    const int c4 = lane * 4;
    const size_t go = ((size_t)b * L_ + l0 + r) * K_ + c4;
    *reinterpret_cast<float4*>(Pw + go) =
        *reinterpret_cast<const float4*>(&pw_l[r][c4]);
    *reinterpret_cast<int4*>(Vx + go) =
        *reinterpret_cast<const int4*>(&vx_l[r][c4]);
    if (lane == 0) nrowG[b * L_ + l0 + r] = nrow_l[r];
  }
}

// ---------------------------------------------------------------------------
// K3: PV + residual, 1 l-row per block, 1024 blocks x 512 threads.
// 8-way j-split, 3-level LDS tree combine.
// ---------------------------------------------------------------------------
__global__ __launch_bounds__(512)
void k_pv_add(const float* __restrict__ hidden,
              const float* __restrict__ Pw,
              const int* __restrict__ Vx,
              const int* __restrict__ nrowG,
              const unsigned char* __restrict__ VT8,
              float* __restrict__ out) {
  __shared__ float pw[K_];        // 1 KB
  __shared__ int   vx[K_];        // 1 KB
  __shared__ float osum[4][H_];   // 12 KB
  __shared__ int   nn;

  const int bid  = blockIdx.x;
  const int l    = bid & 255;
  const int b    = bid >> 8;
  const int t    = threadIdx.x;
  const int wave = t >> 6;
  const int lane = t & 63;
  const size_t go = ((size_t)b * L_ + l) * K_;

  if (t < 64) {
    *reinterpret_cast<float4*>(&pw[t * 4]) =
        *reinterpret_cast<const float4*>(Pw + go + t * 4);
  } else if (t < 128) {
    *reinterpret_cast<int4*>(&vx[(t - 64) * 4]) =
        *reinterpret_cast<const int4*>(Vx + go + (t - 64) * 4);
  } else if (t == 128) {
    nn = nrowG[b * L_ + l];
  }
  __syncthreads();

  const int n = nn;
  float acc[12];
#pragma unroll
  for (int i = 0; i < 12; ++i) acc[i] = 0.f;

#pragma unroll 4
  for (int j = wave; j < n; j += 8) {
    const float wgt = pw[j];                      // LDS broadcast
    const int   idx = vx[j];
    const uint3 v = *reinterpret_cast<const uint3*>(
        VT8 + (size_t)idx * H_ + lane * 12);      // 12B x 64 lanes = 768B row
    float f[12];
    fp8_dec4(v.x, f);
    fp8_dec4(v.y, f + 4);
    fp8_dec4(v.z, f + 8);
#pragma unroll
    for (int i = 0; i < 12; ++i) acc[i] += wgt * f[i];
  }

  // tree combine: 8 -> 4 -> 2 -> store
  if (wave < 4) {
#pragma unroll
    for (int c = 0; c < 3; ++c)
      *reinterpret_cast<float4*>(&osum[wave][lane * 12 + c * 4]) =
          make_float4(acc[c * 4], acc[c * 4 + 1], acc[c * 4 + 2], acc[c * 4 + 3]);
  }
  __syncthreads();
  if (wave >= 4) {
#pragma unroll
    for (int i = 0; i < 12; ++i) osum[wave - 4][lane * 12 + i] += acc[i];
  }
  __syncthreads();
  if (wave < 2) {
#pragma unroll
    for (int i = 0; i < 12; ++i) osum[wave][lane * 12 + i] += osum[wave + 2][lane * 12 + i];
  }
  __syncthreads();

  if (wave == 0) {
    const float* hrow = hidden + ((size_t)b * L_ + l) * H_;
    float*       orow = out    + ((size_t)b * L_ + l) * H_;
#pragma unroll
    for (int c = 0; c < 3; ++c) {
      const int h0 = c * 256 + lane * 4;
      const float4 o0 = *reinterpret_cast<const float4*>(&osum[0][h0]);
      const float4 o1 = *reinterpret_cast<const float4*>(&osum[1][h0]);
      const float4 hv = *reinterpret_cast<const float4*>(hrow + h0);
      *reinterpret_cast<float4*>(orow + h0) =
          make_float4(o0.x + o1.x + hv.x, o0.y + o1.y + hv.y,
                      o0.z + o1.z + hv.z, o0.w + o1.w + hv.w);
    }
  }
}

// ---------------------------------------------------------------------------
extern "C" void kernel_launch(void* const* d_in, const int* in_sizes, int n_in,
                              void* d_out, int out_size, void* d_ws, size_t ws_size,
                              hipStream_t stream) {
  (void)in_sizes; (void)n_in; (void)out_size; (void)ws_size;
  const float* hidden  = (const float*)d_in[0];
  const int*   key_seq = (const int*)d_in[1];
  const int*   vmat    = (const int*)d_in[2];
  const int*   mask    = (const int*)d_in[3];
  const float* key_emb = (const float*)d_in[4];
  const float* val_emb = (const float*)d_in[5];
  float* out = (float*)d_out;

  // ws layout: VT8 | ET2 | Pw | Vx | nrow
  unsigned char* VT8   = (unsigned char*)d_ws;
  unsigned*      ET2   = (unsigned*)(VT8 + VT8_BYTES);
  float*         Pw    = (float*)((char*)ET2 + ET2_BYTES);
  int*           Vx    = (int*)((char*)Pw + PW_BYTES);
  int*           nrowG = (int*)((char*)Vx + VX_BYTES);

  k_gather_keys_T<<<TBLK, 256, 0, stream>>>(key_seq, key_emb, ET2);
  k_scores_conv<<<SBLK + CBLK, 512, 0, stream>>>(hidden, ET2, mask, vmat,
                                                 val_emb, VT8, Pw, Vx, nrowG);
  k_pv_add<<<B_ * L_, 512, 0, stream>>>(hidden, Pw, Vx, nrowG, VT8, out);
}

// Round 12
// 35.106 us; speedup vs baseline: 1.1422x; 1.0934x over previous
//
#include <hip/hip_runtime.h>
#include <hip/hip_cooperative_groups.h>
#include <math.h>

namespace cg = cooperative_groups;

typedef float    f32x2 __attribute__((ext_vector_type(2)));
typedef float    f32x4 __attribute__((ext_vector_type(4)));
typedef _Float16 f16x2 __attribute__((ext_vector_type(2)));

static constexpr int B_ = 4;
static constexpr int L_ = 256;
static constexpr int K_ = 256;
static constexpr int H_ = 768;
static constexpr int H2_ = H_ / 2;       // 384 f16-pairs per row
static constexpr int VAL_SIZE_ = 10000;
static constexpr float INV_TEMPER = 0.03608439182435161f; // 1/sqrt(768)

// ---------------- f16 pair helpers ----------------
__device__ __forceinline__ unsigned pack_f16x2(float a, float b) {
  f16x2 p = {(_Float16)a, (_Float16)b};   // RNE converts
  return __builtin_bit_cast(unsigned, p);
}
__device__ __forceinline__ float fdot2u(unsigned a, unsigned b, float c) {
#if __has_builtin(__builtin_amdgcn_fdot2)
  return __builtin_amdgcn_fdot2(__builtin_bit_cast(f16x2, a),
                                __builtin_bit_cast(f16x2, b), c, false);
#else
  f16x2 va = __builtin_bit_cast(f16x2, a);
  f16x2 vb = __builtin_bit_cast(f16x2, b);
  return c + (float)va.x * (float)vb.x + (float)va.y * (float)vb.y;
#endif
}

// ---------------- non-temporal load (native vec type) ----------------
__device__ __forceinline__ float4 nt_load4(const float* p) {
  f32x4 v = __builtin_nontemporal_load(reinterpret_cast<const f32x4*>(p));
  return make_float4(v.x, v.y, v.z, v.w);
}

// ---------------- fp8 e4m3fn (OCP) helpers ----------------
#if __has_builtin(__builtin_amdgcn_cvt_pk_fp8_f32)
#define HW_FP8_ENC 1
#endif
#if __has_builtin(__builtin_amdgcn_cvt_pk_f32_fp8)
#define HW_FP8_DEC 1
#endif

__device__ __forceinline__ unsigned fp8_enc1(float f) {
  unsigned s = (__float_as_uint(f) >> 31) << 7;
  float af = fminf(fabsf(f), 448.0f);
  unsigned em;
  if (af < 0.015625f) {
    em = (unsigned)rintf(af * 512.0f);
  } else {
    unsigned m = __float_as_uint(af);
    m += 0x7ffffu + ((m >> 20) & 1u);
    em = (m >> 20) - (120u << 3);
  }
  return s | em;
}
__device__ __forceinline__ float fp8_dec1(unsigned b) {
  unsigned em = b & 0x7fu;
  unsigned sbit = (b & 0x80u) << 24;
  float n = __uint_as_float(sbit | ((em + 960u) << 20));
  float sub = __uint_as_float(sbit | 0x3F800000u) * (float)em * 0.001953125f;
  return em >= 8u ? n : sub;
}
__device__ __forceinline__ unsigned fp8_enc4(float a, float b, float c, float d) {
#ifdef HW_FP8_ENC
  int w = 0;
  w = __builtin_amdgcn_cvt_pk_fp8_f32(a, b, w, false);
  w = __builtin_amdgcn_cvt_pk_fp8_f32(c, d, w, true);
  return (unsigned)w;
#else
  return fp8_enc1(a) | (fp8_enc1(b) << 8) | (fp8_enc1(c) << 16) | (fp8_enc1(d) << 24);
#endif
}
__device__ __forceinline__ void fp8_dec4(unsigned w, float* o) {
#ifdef HW_FP8_DEC
  f32x2 lo = __builtin_amdgcn_cvt_pk_f32_fp8((int)w, false);
  f32x2 hi = __builtin_amdgcn_cvt_pk_f32_fp8((int)w, true);
  o[0] = lo.x; o[1] = lo.y; o[2] = hi.x; o[3] = hi.y;
#else
  o[0] = fp8_dec1(w & 0xffu);
  o[1] = fp8_dec1((w >> 8) & 0xffu);
  o[2] = fp8_dec1((w >> 16) & 0xffu);
  o[3] = fp8_dec1(w >> 24);
#endif
}

static constexpr int TBLK = (K_ / 64) * (H_ / 64) * B_;    // 192 transpose tiles
static constexpr int FBLK = (L_ / 2) * B_;                 // 512 fused blocks
static constexpr int CBLK = (VAL_SIZE_ * H_) / 4096;       // 1875 (fallback conv)
static constexpr int CVT_WORDS = VAL_SIZE_ * H_ / 4;       // 1,920,000 uints
static constexpr size_t VT8_BYTES = (size_t)VAL_SIZE_ * H_;     // 7,680,000
static constexpr size_t ET2_BYTES = (size_t)B_ * H2_ * K_ * 4;  // 1,572,864

// ---------------------------------------------------------------------------
// Phase-2 shared state + body (r9-proven numerics): stage -> scores(8x48) ->
// softmax+compact -> PV(2 rows x 4 j-slices) -> tree combine -> residual store.
// ---------------------------------------------------------------------------
struct SharedP2 {
  unsigned hid2[2 * H2_];     // 3 KB
  float4   part[2][8][64];    // 16 KB
  int      vmat_lds[2][K_];   // 2 KB
  float    pw[2][K_];         // 2 KB
  int      vidx[2][K_];       // 2 KB
  float    osum[2][2][H_];    // 12 KB
  int      nrow[2];
};

__device__ __forceinline__ void phase2(SharedP2& s,
                                       const float* __restrict__ hidden,
                                       const unsigned* __restrict__ ET2,
                                       const int* __restrict__ mask,
                                       const int* __restrict__ vmat,
                                       const unsigned char* __restrict__ VT8,
                                       float* __restrict__ out,
                                       const int b, const int l0) {
  const int t    = threadIdx.x;
  const int wave = t >> 6;
  const int lane = t & 63;

  // ---- stage hidden (f16 pairs) + vmat rows ----
  const float* hsrc = hidden + ((size_t)b * L_ + l0) * H_;
  for (int i = t; i < 2 * H2_; i += 512) {
    const float2 hv = *reinterpret_cast<const float2*>(hsrc + 2 * i);
    s.hid2[i] = pack_f16x2(hv.x, hv.y);
  }
  if (t < 128) {
    const int r  = t >> 6;
    const int c4 = lane * 4;
    *reinterpret_cast<int4*>(&s.vmat_lds[r][c4]) =
        *reinterpret_cast<const int4*>(vmat + ((size_t)b * L_ + l0 + r) * K_ + c4);
  }
  __syncthreads();

  // ---- scores: 8 waves x 48 h2 ----
  {
    float4 acc0 = make_float4(0.f, 0.f, 0.f, 0.f);
    float4 acc1 = make_float4(0.f, 0.f, 0.f, 0.f);
    const unsigned* etp =
        ET2 + (size_t)b * H2_ * K_ + (size_t)(wave * 48) * K_ + lane * 4;
#pragma unroll 4
    for (int hh = 0; hh < 48; ++hh) {
      const uint4 e = *reinterpret_cast<const uint4*>(etp + (size_t)hh * K_);
      const unsigned h0 = s.hid2[wave * 48 + hh];
      const unsigned h1 = s.hid2[H2_ + wave * 48 + hh];
      acc0.x = fdot2u(e.x, h0, acc0.x);
      acc0.y = fdot2u(e.y, h0, acc0.y);
      acc0.z = fdot2u(e.z, h0, acc0.z);
      acc0.w = fdot2u(e.w, h0, acc0.w);
      acc1.x = fdot2u(e.x, h1, acc1.x);
      acc1.y = fdot2u(e.y, h1, acc1.y);
      acc1.z = fdot2u(e.z, h1, acc1.z);
      acc1.w = fdot2u(e.w, h1, acc1.w);
    }
    s.part[0][wave][lane] = acc0;
    s.part[1][wave][lane] = acc1;
  }
  __syncthreads();

  // ---- softmax + compaction: waves 0,1 (one per row) ----
  if (t < 128) {
    const int kq2 = lane;
    const int l2  = t >> 6;
    float4 a = s.part[l2][0][kq2];
#pragma unroll
    for (int c = 1; c < 8; ++c) {
      const float4 pc = s.part[l2][c][kq2];
      a.x += pc.x; a.y += pc.y; a.z += pc.z; a.w += pc.w;
    }

    const int lrow = l0 + l2;
    const int4 m4 = *reinterpret_cast<const int4*>(
        mask + ((size_t)b * L_ + lrow) * K_ + kq2 * 4);
    float ex[4];
    ex[0] = (m4.x > 0) ? expf(a.x * INV_TEMPER) : 0.f;
    ex[1] = (m4.y > 0) ? expf(a.y * INV_TEMPER) : 0.f;
    ex[2] = (m4.z > 0) ? expf(a.z * INV_TEMPER) : 0.f;
    ex[3] = (m4.w > 0) ? expf(a.w * INV_TEMPER) : 0.f;

    float sm = ex[0] + ex[1] + ex[2] + ex[3];
#pragma unroll
    for (int off = 32; off > 0; off >>= 1) sm += __shfl_down(sm, off);
    const float tot = __shfl(sm, 0) + 1e-10f;
    const float rtot = 1.0f / tot;

    const unsigned long long lt = (1ull << kq2) - 1ull;
    unsigned long long m[4];
    int run = 0;
    int pos[4];
#pragma unroll
    for (int cc = 0; cc < 4; ++cc) {
      m[cc] = __ballot(ex[cc] != 0.f);
      pos[cc] = run + (int)__popcll(m[cc] & lt);
      run += (int)__popcll(m[cc]);
    }
#pragma unroll
    for (int cc = 0; cc < 4; ++cc) {
      if (ex[cc] != 0.f) {
        s.pw[l2][pos[cc]]   = ex[cc] * rtot;
        s.vidx[l2][pos[cc]] = s.vmat_lds[l2][kq2 * 4 + cc];
      }
    }
    if (kq2 == 0) s.nrow[l2] = run;
  }
  __syncthreads();

  // ---- PV: wave -> row r=wave&1, quarter q=wave>>1 ----
  const int r = wave & 1;
  const int q = wave >> 1;       // 0..3
  const int n = s.nrow[r];

  float acc[12];
#pragma unroll
  for (int i = 0; i < 12; ++i) acc[i] = 0.f;

#pragma unroll 4
  for (int j = q; j < n; j += 4) {
    const float wgt = s.pw[r][j];                 // LDS broadcast
    const int   idx = s.vidx[r][j];
    const uint3 v = *reinterpret_cast<const uint3*>(
        VT8 + (size_t)idx * H_ + lane * 12);      // 12B x 64 lanes = 768B row
    float f[12];
    fp8_dec4(v.x, f);
    fp8_dec4(v.y, f + 4);
    fp8_dec4(v.z, f + 8);
#pragma unroll
    for (int i = 0; i < 12; ++i) acc[i] += wgt * f[i];
  }

  if (q < 2) {
#pragma unroll
    for (int c = 0; c < 3; ++c)
      *reinterpret_cast<float4*>(&s.osum[r][q][lane * 12 + c * 4]) =
          make_float4(acc[c * 4], acc[c * 4 + 1], acc[c * 4 + 2], acc[c * 4 + 3]);
  }
  __syncthreads();
  if (q >= 2) {
#pragma unroll
    for (int i = 0; i < 12; ++i) s.osum[r][q - 2][lane * 12 + i] += acc[i];
  }
  __syncthreads();

  if (q == 0) {
    const float* hrow = hidden + ((size_t)b * L_ + l0 + r) * H_;
    float*       orow = out    + ((size_t)b * L_ + l0 + r) * H_;
#pragma unroll
    for (int c = 0; c < 3; ++c) {
      const int h0 = c * 256 + lane * 4;
      const float4 o0 = *reinterpret_cast<const float4*>(&s.osum[r][0][h0]);
      const float4 o1 = *reinterpret_cast<const float4*>(&s.osum[r][1][h0]);
      const float4 hv = *reinterpret_cast<const float4*>(hrow + h0);
      *reinterpret_cast<float4*>(orow + h0) =
          make_float4(o0.x + o1.x + hv.x, o0.y + o1.y + hv.y,
                      o0.z + o1.z + hv.z, o0.w + o1.w + hv.w);
    }
  }
}

// ---------------------------------------------------------------------------
// Cooperative single kernel: phase 1 = convert (whole grid, strided) +
// transpose (blocks 0..TBLK-1, threads 0..255); grid.sync(); phase 2 = r9
// fused scores->softmax->PV. 512 blocks x 512 threads, 2 blocks/CU.
// ---------------------------------------------------------------------------
__global__ __launch_bounds__(512, 4)
void k_all(const float* __restrict__ hidden,
           const int* __restrict__ key_seq,
           const int* __restrict__ vmat,
           const int* __restrict__ mask,
           const float* __restrict__ key_emb,
           const float* __restrict__ vtab,
           unsigned* __restrict__ ET2,
           unsigned char* __restrict__ VT8,
           float* __restrict__ out) {
  __shared__ float    tile[64][65];   // 16.6 KB (phase 1 only)
  __shared__ SharedP2 s2;             // 37.5 KB

  const int t    = threadIdx.x;
  const int bid  = blockIdx.x;
  const int lane = t & 63;

  // ---- phase 1a: val-table convert, whole grid ----
  {
    const int gtid = bid * 512 + t;
#pragma unroll
    for (int i = 0; i < 8; ++i) {
      const int w = i * (FBLK * 512) + gtid;
      if (w < CVT_WORDS) {
        const float4 a = nt_load4(vtab + (size_t)w * 4);
        *reinterpret_cast<unsigned*>(VT8 + (size_t)w * 4) =
            fp8_enc4(a.x, a.y, a.z, a.w);
      }
    }
  }

  // ---- phase 1b: key gather+transpose, blocks 0..TBLK-1 (threads 0..255) ----
  if (bid < TBLK && t < 256) {
    const int kb  = (bid % (K_ / 64)) * 64;
    const int hb  = ((bid / (K_ / 64)) % (H_ / 64)) * 64;
    const int bb  = bid / ((K_ / 64) * (H_ / 64));
    const int sub = t >> 6;
#pragma unroll
    for (int p = 0; p < 16; ++p) {
      const int kl  = p * 4 + sub;
      const int row = key_seq[bb * K_ + kb + kl];              // wave-uniform
      tile[kl][lane] = key_emb[(size_t)row * H_ + hb + lane];  // coalesced
    }
  }
  __syncthreads();
  if (bid < TBLK && t < 256) {
    const int kb  = (bid % (K_ / 64)) * 64;
    const int hb  = ((bid / (K_ / 64)) % (H_ / 64)) * 64;
    const int bb  = bid / ((K_ / 64) * (H_ / 64));
    const int sub = t >> 6;
#pragma unroll
    for (int p = 0; p < 8; ++p) {
      const int hl2 = p * 4 + sub;
      ET2[((size_t)bb * H2_ + (hb >> 1) + hl2) * K_ + kb + lane] =
          pack_f16x2(tile[lane][2 * hl2], tile[lane][2 * hl2 + 1]);
    }
  }

  // ---- grid barrier: ET2 + VT8 complete, device-visible ----
  __threadfence();
  cg::this_grid().sync();

  // ---- phase 2 ----
  const int l0 = (bid & 127) * 2;
  const int b  = bid >> 7;
  phase2(s2, hidden, ET2, mask, vmat, VT8, out, b, l0);
}

// ---------------------------------------------------------------------------
// Fallback path (r9-proven): k_prep (transpose + convert) + k_fused2 (phase 2).
// ---------------------------------------------------------------------------
__global__ __launch_bounds__(256)
void k_prep(const int* __restrict__ key_seq,
            const float* __restrict__ key_emb,
            const float* __restrict__ vtab,
            unsigned* __restrict__ ET2,
            unsigned char* __restrict__ VT8) {
  __shared__ float tile[64][65];
  const int t = threadIdx.x;

  if (blockIdx.x >= TBLK) {
    const size_t base = (size_t)(blockIdx.x - TBLK) * 4096;
#pragma unroll
    for (int c = 0; c < 4; ++c) {
      const size_t e0 = base + (size_t)c * 1024 + (size_t)t * 4;
      const float4 a = nt_load4(vtab + e0);
      *reinterpret_cast<unsigned*>(VT8 + e0) = fp8_enc4(a.x, a.y, a.z, a.w);
    }
    return;
  }

  const int blk  = blockIdx.x;
  const int kb   = (blk % (K_ / 64)) * 64;
  const int hb   = ((blk / (K_ / 64)) % (H_ / 64)) * 64;
  const int b    = blk / ((K_ / 64) * (H_ / 64));
  const int sub  = t >> 6;
  const int lane = t & 63;

#pragma unroll
  for (int p = 0; p < 16; ++p) {
    const int kl  = p * 4 + sub;
    const int row = key_seq[b * K_ + kb + kl];
    tile[kl][lane] = key_emb[(size_t)row * H_ + hb + lane];
  }
  __syncthreads();
#pragma unroll
  for (int p = 0; p < 8; ++p) {
    const int hl2 = p * 4 + sub;
    ET2[((size_t)b * H2_ + (hb >> 1) + hl2) * K_ + kb + lane] =
        pack_f16x2(tile[lane][2 * hl2], tile[lane][2 * hl2 + 1]);
  }
}

__global__ __launch_bounds__(512, 4)
void k_fused2(const float* __restrict__ hidden,
              const unsigned* __restrict__ ET2,
              const int* __restrict__ mask,
              const int* __restrict__ vmat,
              const unsigned char* __restrict__ VT8,
              float* __restrict__ out) {
  __shared__ SharedP2 s2;
  const int l0 = ((int)blockIdx.x & 127) * 2;
  const int b  = (int)blockIdx.x >> 7;
  phase2(s2, hidden, ET2, mask, vmat, VT8, out, b, l0);
}

// ---------------------------------------------------------------------------
extern "C" void kernel_launch(void* const* d_in, const int* in_sizes, int n_in,
                              void* d_out, int out_size, void* d_ws, size_t ws_size,
                              hipStream_t stream) {
  (void)in_sizes; (void)n_in; (void)out_size; (void)ws_size;
  const float* hidden  = (const float*)d_in[0];
  const int*   key_seq = (const int*)d_in[1];
  const int*   vmat    = (const int*)d_in[2];
  const int*   mask    = (const int*)d_in[3];
  const float* key_emb = (const float*)d_in[4];
  const float* vtab    = (const float*)d_in[5];
  float* out = (float*)d_out;

  unsigned char* VT8 = (unsigned char*)d_ws;
  unsigned*      ET2 = (unsigned*)(VT8 + VT8_BYTES);

  // Cooperative path requires HW support + all 512 blocks co-resident.
  int dev = 0;
  hipGetDevice(&dev);
  int coop = 0;
  hipDeviceGetAttribute(&coop, hipDeviceAttributeCooperativeLaunch, dev);
  int occ = 0;
  hipError_t oe = hipOccupancyMaxActiveBlocksPerMultiprocessor(&occ, k_all, 512, 0);

  bool done = false;
  if (coop && oe == hipSuccess && occ >= 2) {
    void* args[] = {(void*)&hidden, (void*)&key_seq, (void*)&vmat, (void*)&mask,
                    (void*)&key_emb, (void*)&vtab, (void*)&ET2, (void*)&VT8,
                    (void*)&out};
    hipError_t le = hipLaunchCooperativeKernel((const void*)k_all, dim3(FBLK),
                                               dim3(512), args, 0u, stream);
    done = (le == hipSuccess);
  }
  if (!done) {
    k_prep<<<TBLK + CBLK, 256, 0, stream>>>(key_seq, key_emb, vtab, ET2, VT8);
    k_fused2<<<FBLK, 512, 0, stream>>>(hidden, ET2, mask, vmat, VT8, out);
  }
}